// Round 7
// baseline (171.226 us; speedup 1.0000x reference)
//
#include <hip/hip_runtime.h>
#include <hip/hip_bf16.h>

// GraphAttentionLayer fused kernels for MI355X (gfx950).
// N=8192, IN=512, OUT=64. adj read (256MB @ ~6.9TB/s) is the HBM floor (~39us).
// K-A: Wh = h@W (fp32), Wh1L/W2L rank-1 score vectors (log2-scaled),
//      WhbT bf16 [64][8192].
// K-B: attn_partial: fused mask+softmax-numerator+PV, NO max subtraction
//      (|s|<=~35 in log2 domain -> 2^s safe in fp32; division normalizes).
//      1024 blocks x 4 waves (16 rows, col-half per block) = 4 blocks/CU,
//      depth-2 adj register prefetch, mfma_f32_16x16x32_bf16.
// K-C: combine halves + divide by l + ELU.

#define LOG2E 1.4426950408889634f

typedef __attribute__((ext_vector_type(8))) short  short8v;
typedef __attribute__((ext_vector_type(4))) float  f32x4;

__device__ __forceinline__ unsigned short f2bf(float f) {
    union { float f; unsigned int u; } x; x.f = f;
    unsigned int r = x.u + 0x7FFFu + ((x.u >> 16) & 1u);   // RNE
    return (unsigned short)(r >> 16);
}

// ---------------- Kernel A: Wh, Wh1L, W2L, WhbT ----------------
// grid 1024 x 256. Each wave: 2 rows. 4096 waves -> 4 waves/SIMD.
__global__ __launch_bounds__(256) void wh_kernel(
        const float* __restrict__ h, const float* __restrict__ W,
        const float* __restrict__ a,
        unsigned short* __restrict__ WhbT,
        float* __restrict__ Wh1L, float* __restrict__ W2L) {
    const int wave = threadIdx.x >> 6;
    const int lane = threadIdx.x & 63;
    const int row0 = (blockIdx.x * 4 + wave) * 2;

    float acc0 = 0.f, acc1 = 0.f;
    const float* h0 = h + (size_t)row0 * 512;
    const float* h1 = h0 + 512;
    for (int i = 0; i < 512; i += 4) {
        float w0 = W[(i + 0) * 64 + lane];
        float w1 = W[(i + 1) * 64 + lane];
        float w2 = W[(i + 2) * 64 + lane];
        float w3 = W[(i + 3) * 64 + lane];
        float4 hv0 = *reinterpret_cast<const float4*>(h0 + i);
        float4 hv1 = *reinterpret_cast<const float4*>(h1 + i);
        acc0 = fmaf(hv0.x, w0, fmaf(hv0.y, w1, fmaf(hv0.z, w2, fmaf(hv0.w, w3, acc0))));
        acc1 = fmaf(hv1.x, w0, fmaf(hv1.y, w1, fmaf(hv1.z, w2, fmaf(hv1.w, w3, acc1))));
    }

    ushort2 bt;
    bt.x = f2bf(acc0);
    bt.y = f2bf(acc1);
    *reinterpret_cast<ushort2*>(WhbT + (size_t)lane * 8192 + row0) = bt;

    const float a1 = a[lane] * LOG2E, a2 = a[lane + 64] * LOG2E;
    float t10 = acc0 * a1, t20 = acc0 * a2;
    float t11 = acc1 * a1, t21 = acc1 * a2;
#pragma unroll
    for (int off = 32; off; off >>= 1) {
        t10 += __shfl_xor(t10, off);
        t20 += __shfl_xor(t20, off);
        t11 += __shfl_xor(t11, off);
        t21 += __shfl_xor(t21, off);
    }
    if (lane == 0) {
        Wh1L[row0] = t10; Wh1L[row0 + 1] = t11;
        W2L[row0]  = t20; W2L[row0 + 1]  = t21;
    }
}

// ---------------- Kernel B: partial mask+softmax-numerator+PV ----------------
// grid 1024 x 256 (4 waves). Block b: rows [ (b>>1)*16 .. +16 ), cols
// [ (b&1)*4096 .. +4096 ). Waves split the 4096 cols: per iter the block
// covers 128 cols, 32 iters. Partial acc & l are plain sums (no max), written
// to workspace: ws[g2h][R*64+col] (1024 floats) + ws[g2h][1024+R] (16 floats).
#define WSTRIDE 1040
__global__ __launch_bounds__(256, 4) void attn_partial(
        const int* __restrict__ adj,
        const unsigned short* __restrict__ WhbT,
        const float* __restrict__ Wh1L, const float* __restrict__ W2L,
        float* __restrict__ ws) {
    __shared__ float sm_acc[4][64][17];
    __shared__ float sm_l[4][16];

    const int w    = threadIdx.x >> 6;
    const int lane = threadIdx.x & 63;
    const int r    = lane & 15;       // A-frag row / D col
    const int cg   = lane >> 4;       // k-chunk group
    const int g2h  = blockIdx.x;
    const int i0   = (g2h >> 1) * 16;
    const int coff = (g2h & 1) * 4096;
    const int row  = i0 + r;

    const float wh1 = Wh1L[row];

    f32x4 acc[4];
#pragma unroll
    for (int f = 0; f < 4; ++f) acc[f] = (f32x4){0.f, 0.f, 0.f, 0.f};
    float lsum = 0.f;

    const int off0 = w * 32 + cg * 8;
    const int*            adjp = adj + (size_t)row * 8192 + coff + off0;
    const float*          w2p  = W2L + coff + off0;
    const unsigned short* bp   = WhbT + (size_t)r * 8192 + coff + off0;

    auto body = [&](int it, int4 a0, int4 a1) {
        float4 w20 = *reinterpret_cast<const float4*>(w2p + it * 128);
        float4 w21 = *reinterpret_cast<const float4*>(w2p + it * 128 + 4);

        float p[8];
        {
            float t;
            t = wh1 + w20.x; t = fmaxf(t, 0.2f * t); p[0] = a0.x > 0 ? __builtin_exp2f(t) : 0.f;
            t = wh1 + w20.y; t = fmaxf(t, 0.2f * t); p[1] = a0.y > 0 ? __builtin_exp2f(t) : 0.f;
            t = wh1 + w20.z; t = fmaxf(t, 0.2f * t); p[2] = a0.z > 0 ? __builtin_exp2f(t) : 0.f;
            t = wh1 + w20.w; t = fmaxf(t, 0.2f * t); p[3] = a0.w > 0 ? __builtin_exp2f(t) : 0.f;
            t = wh1 + w21.x; t = fmaxf(t, 0.2f * t); p[4] = a1.x > 0 ? __builtin_exp2f(t) : 0.f;
            t = wh1 + w21.y; t = fmaxf(t, 0.2f * t); p[5] = a1.y > 0 ? __builtin_exp2f(t) : 0.f;
            t = wh1 + w21.z; t = fmaxf(t, 0.2f * t); p[6] = a1.z > 0 ? __builtin_exp2f(t) : 0.f;
            t = wh1 + w21.w; t = fmaxf(t, 0.2f * t); p[7] = a1.w > 0 ? __builtin_exp2f(t) : 0.f;
        }
        lsum += ((p[0] + p[1]) + (p[2] + p[3])) + ((p[4] + p[5]) + (p[6] + p[7]));

        union { short8v s8; __hip_bfloat162 h2[4]; } afu;
        afu.h2[0] = __float22bfloat162_rn(float2{p[0], p[1]});
        afu.h2[1] = __float22bfloat162_rn(float2{p[2], p[3]});
        afu.h2[2] = __float22bfloat162_rn(float2{p[4], p[5]});
        afu.h2[3] = __float22bfloat162_rn(float2{p[6], p[7]});

        const unsigned short* bpi = bp + it * 128;
#pragma unroll
        for (int f = 0; f < 4; ++f) {
            short8v bf = *reinterpret_cast<const short8v*>(bpi + (size_t)f * 16 * 8192);
            acc[f] = __builtin_amdgcn_mfma_f32_16x16x32_bf16(afu.s8, bf, acc[f], 0, 0, 0);
        }
    };

    // depth-2 register prefetch on the adj stream (the only HBM stream)
    int4 qa0 = *reinterpret_cast<const int4*>(adjp);
    int4 qa1 = *reinterpret_cast<const int4*>(adjp + 4);
    int4 qb0 = *reinterpret_cast<const int4*>(adjp + 128);
    int4 qb1 = *reinterpret_cast<const int4*>(adjp + 128 + 4);

    for (int it = 0; it < 32; it += 2) {
        const int4 a0 = qa0, a1 = qa1;
        if (it + 2 < 32) {
            qa0 = *reinterpret_cast<const int4*>(adjp + (it + 2) * 128);
            qa1 = *reinterpret_cast<const int4*>(adjp + (it + 2) * 128 + 4);
        }
        body(it, a0, a1);
        const int4 b0 = qb0, b1 = qb1;
        if (it + 3 < 32) {
            qb0 = *reinterpret_cast<const int4*>(adjp + (it + 3) * 128);
            qb1 = *reinterpret_cast<const int4*>(adjp + (it + 3) * 128 + 4);
        }
        body(it + 1, b0, b1);
    }

    // ---- combine 4 waves' partials (plain sums) ----
    float ls = lsum;
    ls += __shfl_xor(ls, 16);
    ls += __shfl_xor(ls, 32);
    if (lane < 16) sm_l[w][lane] = ls;
#pragma unroll
    for (int f = 0; f < 4; ++f)
#pragma unroll
        for (int reg = 0; reg < 4; ++reg)
            sm_acc[w][lane][f * 4 + reg] = acc[f][reg];
    __syncthreads();

    float* wsb = ws + (size_t)g2h * WSTRIDE;
#pragma unroll
    for (int ss = 0; ss < 4; ++ss) {
        const int s = 4 * w + ss;
        const int f = s >> 2, reg = s & 3;
        float sum = 0.f;
#pragma unroll
        for (int ww = 0; ww < 4; ++ww) sum += sm_acc[ww][lane][s];
        const int R = 4 * cg + reg;
        wsb[R * 64 + 16 * f + r] = sum;
    }
    if (w == 0 && lane < 16) {
        float lrow = sm_l[0][lane] + sm_l[1][lane] + sm_l[2][lane] + sm_l[3][lane];
        wsb[1024 + lane] = lrow;
    }
}

// ---------------- Kernel C: combine halves, normalize, ELU ----------------
// grid 2048 x 256: thread -> one output element (row-major, col fastest).
__global__ __launch_bounds__(256) void combine_kernel(
        const float* __restrict__ ws, float* __restrict__ out) {
    const int idx = blockIdx.x * 256 + threadIdx.x;
    const int row = idx >> 6;
    const int col = idx & 63;
    const int g   = row >> 4;
    const int R   = row & 15;
    const float* b0 = ws + (size_t)(g * 2) * WSTRIDE;
    const float* b1 = b0 + WSTRIDE;
    float v = b0[R * 64 + col] + b1[R * 64 + col];
    float l = b0[1024 + R] + b1[1024 + R];
    float y = v / l;
    y = y > 0.f ? y : expm1f(y);   // ELU, alpha=1
    out[idx] = y;
}

extern "C" void kernel_launch(void* const* d_in, const int* in_sizes, int n_in,
                              void* d_out, int out_size, void* d_ws, size_t ws_size,
                              hipStream_t stream) {
    const float* h   = (const float*)d_in[0];
    const int*   adj = (const int*)d_in[1];
    const float* W   = (const float*)d_in[2];
    const float* a   = (const float*)d_in[3];

    unsigned short* WhbT = (unsigned short*)d_ws;                    // 1 MB
    float* Wh1L = (float*)((char*)d_ws + (1 << 20));                 // 32 KB
    float* W2L  = Wh1L + 8192;                                       // 32 KB
    float* wsp  = (float*)((char*)d_ws + (2 << 20));                 // 1024*1040*4 B

    wh_kernel<<<1024, 256, 0, stream>>>(h, W, a, WhbT, Wh1L, W2L);
    attn_partial<<<1024, 256, 0, stream>>>(adj, WhbT, Wh1L, W2L, wsp);
    combine_kernel<<<2048, 256, 0, stream>>>(wsp, (float*)d_out);
}

// Round 8
// 155.448 us; speedup vs baseline: 1.1015x; 1.1015x over previous
//
#include <hip/hip_runtime.h>
#include <hip/hip_bf16.h>

// GraphAttentionLayer fused kernels for MI355X (gfx950).
// N=8192, IN=512, OUT=64. adj read (256MB @ ~6.9TB/s) is the HBM floor (~39us).
// Round 8: r2's winning GEOMETRY (wh: 256 blocks x 8 rows/wave; attn: 512
// blocks x 4 waves, 16 rows x full 8192 cols) + the lean no-max loop
// (p = 2^s directly, |s| bounded, division normalizes), l via a 5th MFMA
// against a ones-fragment, depth-2 adj register prefetch, 2 dispatches.

#define LOG2E 1.4426950408889634f

typedef __attribute__((ext_vector_type(8))) short  short8v;
typedef __attribute__((ext_vector_type(8))) unsigned short ushort8v;
typedef __attribute__((ext_vector_type(4))) float  f32x4;

__device__ __forceinline__ unsigned short f2bf(float f) {
    union { float f; unsigned int u; } x; x.f = f;
    unsigned int r = x.u + 0x7FFFu + ((x.u >> 16) & 1u);   // RNE
    return (unsigned short)(r >> 16);
}

// ---------------- Kernel A: Wh, Wh1L, W2L, WhbT ----------------
// grid 256 x 256 (4 waves). Each wave: 8 rows; lane = output col.
// 8-row amortization of the W column loads (r2 shape).
__global__ __launch_bounds__(256) void wh_kernel(
        const float* __restrict__ h, const float* __restrict__ W,
        const float* __restrict__ a,
        unsigned short* __restrict__ WhbT,
        float* __restrict__ Wh1L, float* __restrict__ W2L) {
    const int wave = threadIdx.x >> 6;
    const int lane = threadIdx.x & 63;
    const int row0 = (blockIdx.x * 4 + wave) * 8;

    float acc[8];
#pragma unroll
    for (int rr = 0; rr < 8; ++rr) acc[rr] = 0.f;

    const float* hrow = h + (size_t)row0 * 512;
    for (int i = 0; i < 512; i += 4) {
        float w0 = W[(i + 0) * 64 + lane];
        float w1 = W[(i + 1) * 64 + lane];
        float w2 = W[(i + 2) * 64 + lane];
        float w3 = W[(i + 3) * 64 + lane];
#pragma unroll
        for (int rr = 0; rr < 8; ++rr) {
            float4 hv = *reinterpret_cast<const float4*>(hrow + (size_t)rr * 512 + i);
            acc[rr] = fmaf(hv.x, w0, fmaf(hv.y, w1, fmaf(hv.z, w2, fmaf(hv.w, w3, acc[rr]))));
        }
    }

    // WhbT[col][row] bf16, 16B store per lane
    ushort8v bt;
#pragma unroll
    for (int rr = 0; rr < 8; ++rr) bt[rr] = f2bf(acc[rr]);
    *reinterpret_cast<ushort8v*>(WhbT + (size_t)lane * 8192 + row0) = bt;

    // rank-1 score vectors, pre-scaled by log2(e)
    const float a1 = a[lane] * LOG2E, a2 = a[lane + 64] * LOG2E;
#pragma unroll
    for (int rr = 0; rr < 8; ++rr) {
        float t1 = acc[rr] * a1;
        float t2 = acc[rr] * a2;
#pragma unroll
        for (int off = 32; off; off >>= 1) {
            t1 += __shfl_xor(t1, off);
            t2 += __shfl_xor(t2, off);
        }
        if (lane == 0) { Wh1L[row0 + rr] = t1; W2L[row0 + rr] = t2; }
    }
}

// ---------------- Kernel B: fused mask + softmax + PV ----------------
// grid 512 x 256 (4 waves). Block owns 16 rows x full 8192 cols; waves split
// the cols: per round the block covers 128 cols, 64 rounds (r2 geometry).
// No max subtraction (log2-domain scores bounded, division normalizes).
// l accumulated by a 5th MFMA against a ones-fragment (off the VALU pipe).
__global__ __launch_bounds__(256) void attn_kernel(
        const int* __restrict__ adj,
        const unsigned short* __restrict__ WhbT,
        const float* __restrict__ Wh1L, const float* __restrict__ W2L,
        float* __restrict__ out) {
    __shared__ float sm_acc[4][64][17];   // padded
    __shared__ float sm_l[4][16];

    const int w    = threadIdx.x >> 6;
    const int lane = threadIdx.x & 63;
    const int r    = lane & 15;       // A-frag row / D col-part
    const int cg   = lane >> 4;       // k-chunk group
    const int i0   = blockIdx.x * 16;
    const int row  = i0 + r;

    const float wh1 = Wh1L[row];

    f32x4 acc[4];
#pragma unroll
    for (int f = 0; f < 4; ++f) acc[f] = (f32x4){0.f, 0.f, 0.f, 0.f};
    f32x4 accl = (f32x4){0.f, 0.f, 0.f, 0.f};

    short8v ones;
#pragma unroll
    for (int b = 0; b < 8; ++b) ones[b] = (short)0x3F80;   // bf16 1.0

    const int off0 = w * 32 + cg * 8;
    const int*            adjp = adj + (size_t)row * 8192 + off0;
    const float*          w2p  = W2L + off0;
    const unsigned short* bp   = WhbT + (size_t)r * 8192 + off0;

    auto body = [&](int it, int4 a0, int4 a1) {
        float4 w20 = *reinterpret_cast<const float4*>(w2p + it * 128);
        float4 w21 = *reinterpret_cast<const float4*>(w2p + it * 128 + 4);

        float p[8];
        {
            float t;
            t = wh1 + w20.x; t = fmaxf(t, 0.2f * t); p[0] = a0.x > 0 ? __builtin_exp2f(t) : 0.f;
            t = wh1 + w20.y; t = fmaxf(t, 0.2f * t); p[1] = a0.y > 0 ? __builtin_exp2f(t) : 0.f;
            t = wh1 + w20.z; t = fmaxf(t, 0.2f * t); p[2] = a0.z > 0 ? __builtin_exp2f(t) : 0.f;
            t = wh1 + w20.w; t = fmaxf(t, 0.2f * t); p[3] = a0.w > 0 ? __builtin_exp2f(t) : 0.f;
            t = wh1 + w21.x; t = fmaxf(t, 0.2f * t); p[4] = a1.x > 0 ? __builtin_exp2f(t) : 0.f;
            t = wh1 + w21.y; t = fmaxf(t, 0.2f * t); p[5] = a1.y > 0 ? __builtin_exp2f(t) : 0.f;
            t = wh1 + w21.z; t = fmaxf(t, 0.2f * t); p[6] = a1.z > 0 ? __builtin_exp2f(t) : 0.f;
            t = wh1 + w21.w; t = fmaxf(t, 0.2f * t); p[7] = a1.w > 0 ? __builtin_exp2f(t) : 0.f;
        }

        union { short8v s8; __hip_bfloat162 h2[4]; } afu;
        afu.h2[0] = __float22bfloat162_rn(float2{p[0], p[1]});
        afu.h2[1] = __float22bfloat162_rn(float2{p[2], p[3]});
        afu.h2[2] = __float22bfloat162_rn(float2{p[4], p[5]});
        afu.h2[3] = __float22bfloat162_rn(float2{p[6], p[7]});

        const unsigned short* bpi = bp + it * 128;
#pragma unroll
        for (int f = 0; f < 4; ++f) {
            short8v bf = *reinterpret_cast<const short8v*>(bpi + (size_t)f * 16 * 8192);
            acc[f] = __builtin_amdgcn_mfma_f32_16x16x32_bf16(afu.s8, bf, acc[f], 0, 0, 0);
        }
        accl = __builtin_amdgcn_mfma_f32_16x16x32_bf16(afu.s8, ones, accl, 0, 0, 0);
    };

    // depth-2 register prefetch on the adj stream (the only HBM stream)
    int4 qa0 = *reinterpret_cast<const int4*>(adjp);
    int4 qa1 = *reinterpret_cast<const int4*>(adjp + 4);
    int4 qb0 = *reinterpret_cast<const int4*>(adjp + 128);
    int4 qb1 = *reinterpret_cast<const int4*>(adjp + 128 + 4);

    for (int it = 0; it < 64; it += 2) {
        const int4 a0 = qa0, a1 = qa1;
        if (it + 2 < 64) {
            qa0 = *reinterpret_cast<const int4*>(adjp + (it + 2) * 128);
            qa1 = *reinterpret_cast<const int4*>(adjp + (it + 2) * 128 + 4);
        }
        body(it, a0, a1);
        const int4 b0 = qb0, b1 = qb1;
        if (it + 3 < 64) {
            qb0 = *reinterpret_cast<const int4*>(adjp + (it + 3) * 128);
            qb1 = *reinterpret_cast<const int4*>(adjp + (it + 3) * 128 + 4);
        }
        body(it + 1, b0, b1);
    }

    // ---- combine 4 waves' partials (plain sums; fixed implicit max) ----
    if (r == 0) {
#pragma unroll
        for (int reg = 0; reg < 4; ++reg) sm_l[w][4 * cg + reg] = accl[reg];
    }
#pragma unroll
    for (int f = 0; f < 4; ++f)
#pragma unroll
        for (int reg = 0; reg < 4; ++reg)
            sm_acc[w][lane][f * 4 + reg] = acc[f][reg];
    __syncthreads();

#pragma unroll
    for (int ss = 0; ss < 4; ++ss) {
        const int s = 4 * w + ss;          // f = w, reg = ss
        float sum = 0.f;
#pragma unroll
        for (int ww = 0; ww < 4; ++ww) sum += sm_acc[ww][lane][s];
        const int R = 4 * cg + ss;
        float lrow = sm_l[0][R] + sm_l[1][R] + sm_l[2][R] + sm_l[3][R];
        float y = sum / lrow;
        y = y > 0.f ? y : expm1f(y);       // ELU, alpha=1
        out[(size_t)(i0 + R) * 64 + 16 * w + r] = y;
    }
}

extern "C" void kernel_launch(void* const* d_in, const int* in_sizes, int n_in,
                              void* d_out, int out_size, void* d_ws, size_t ws_size,
                              hipStream_t stream) {
    const float* h   = (const float*)d_in[0];
    const int*   adj = (const int*)d_in[1];
    const float* W   = (const float*)d_in[2];
    const float* a   = (const float*)d_in[3];

    unsigned short* WhbT = (unsigned short*)d_ws;                    // 1 MB
    float* Wh1L = (float*)((char*)d_ws + (1 << 20));                 // 32 KB
    float* W2L  = Wh1L + 8192;                                       // 32 KB

    wh_kernel<<<256, 256, 0, stream>>>(h, W, a, WhbT, Wh1L, W2L);
    attn_kernel<<<512, 256, 0, stream>>>(adj, WhbT, Wh1L, W2L, (float*)d_out);
}

// Round 9
// 128.847 us; speedup vs baseline: 1.3289x; 1.2065x over previous
//
#include <hip/hip_runtime.h>
#include <hip/hip_bf16.h>

// GraphAttentionLayer fused kernels for MI355X (gfx950).
// N=8192, IN=512, OUT=64. adj (256MB) is the only HBM-scale stream (~39us floor).
// r8 diagnosis: attn latency-bound (155us at 11% HBM, 80% idle) — vmcnt FIFO
// trap: slow adj loads issued before fast L2 loads get force-drained every
// iteration. r9 fix: LDS-staged pipeline. Per 256-col tile: [8 fast bf loads]
// [5 global_load_lds stage(t+2)] [vmcnt(18), raw barrier] [P-phase from LDS]
// [lgkmcnt(0), raw barrier] [8 MFMA]. Fast-before-slow order => counted waits;
// raw barriers keep stages in flight. adj/P LDS XOR-swizzled (16B chunks).

#define LOG2E 1.4426950408889634f

typedef __attribute__((ext_vector_type(8))) short  short8v;
typedef __attribute__((ext_vector_type(8))) unsigned short ushort8v;
typedef __attribute__((ext_vector_type(4))) float  f32x4;

__device__ __forceinline__ unsigned short f2bf(float f) {
    union { float f; unsigned int u; } x; x.f = f;
    unsigned int r = x.u + 0x7FFFu + ((x.u >> 16) & 1u);   // RNE
    return (unsigned short)(r >> 16);
}

// ---------------- Kernel A: Wh, Wh1L, W2L, WhbT (r8, unchanged) ----------------
__global__ __launch_bounds__(256) void wh_kernel(
        const float* __restrict__ h, const float* __restrict__ W,
        const float* __restrict__ a,
        unsigned short* __restrict__ WhbT,
        float* __restrict__ Wh1L, float* __restrict__ W2L) {
    const int wave = threadIdx.x >> 6;
    const int lane = threadIdx.x & 63;
    const int row0 = (blockIdx.x * 4 + wave) * 8;

    float acc[8];
#pragma unroll
    for (int rr = 0; rr < 8; ++rr) acc[rr] = 0.f;

    const float* hrow = h + (size_t)row0 * 512;
    for (int i = 0; i < 512; i += 4) {
        float w0 = W[(i + 0) * 64 + lane];
        float w1 = W[(i + 1) * 64 + lane];
        float w2 = W[(i + 2) * 64 + lane];
        float w3 = W[(i + 3) * 64 + lane];
#pragma unroll
        for (int rr = 0; rr < 8; ++rr) {
            float4 hv = *reinterpret_cast<const float4*>(hrow + (size_t)rr * 512 + i);
            acc[rr] = fmaf(hv.x, w0, fmaf(hv.y, w1, fmaf(hv.z, w2, fmaf(hv.w, w3, acc[rr]))));
        }
    }

    ushort8v bt;
#pragma unroll
    for (int rr = 0; rr < 8; ++rr) bt[rr] = f2bf(acc[rr]);
    *reinterpret_cast<ushort8v*>(WhbT + (size_t)lane * 8192 + row0) = bt;

    const float a1 = a[lane] * LOG2E, a2 = a[lane + 64] * LOG2E;
#pragma unroll
    for (int rr = 0; rr < 8; ++rr) {
        float t1 = acc[rr] * a1;
        float t2 = acc[rr] * a2;
#pragma unroll
        for (int off = 32; off; off >>= 1) {
            t1 += __shfl_xor(t1, off);
            t2 += __shfl_xor(t2, off);
        }
        if (lane == 0) { Wh1L[row0 + rr] = t1; W2L[row0 + rr] = t2; }
    }
}

// ---------------- Kernel B: LDS-pipelined mask+softmax+PV ----------------
// grid 512 x 256 (4 waves). Block: 16 rows x 8192 cols, 32 tiles of 256 cols.
__global__ __launch_bounds__(256) void attn_kernel(
        const int* __restrict__ adj,
        const unsigned short* __restrict__ WhbT,
        const float* __restrict__ Wh1L, const float* __restrict__ W2L,
        float* __restrict__ out) {
    __shared__ int            adj_lds[3][16][256];   // 48 KB, 16B-chunk swizzled
    __shared__ float          w2_lds[3][256];        // 3 KB
    __shared__ unsigned short p_lds[16][256];        // 8 KB, 16B-chunk swizzled
    __shared__ float          sm_l[4][16];

    const int w    = threadIdx.x >> 6;
    const int lane = threadIdx.x & 63;
    const int fr   = lane & 15;      // A m-row (query row) / B-C n (feature)
    const int q    = lane >> 4;      // k-group
    const int i0   = blockIdx.x * 16;
    const int sw   = fr & 7;         // LDS swizzle key for row fr

    const float wh1 = Wh1L[i0 + fr];

    // staged-adj per-lane global sources, rows 4w..4w+3, source pre-swizzled
    const int* asrc[4];
#pragma unroll
    for (int rr = 0; rr < 4; ++rr) {
        const int row = 4 * w + rr, s = row & 7;
        asrc[rr] = adj + (size_t)(i0 + row) * 8192 + ((lane ^ s) << 2);
    }
    const float*          wsrc = W2L + w * 64 + lane;
    const unsigned short* bsrc = WhbT + (size_t)(16 * w + fr) * 8192 + q * 8;

    f32x4 acc = (f32x4){0.f, 0.f, 0.f, 0.f};
    float lsum = 0.f;

#define STAGE(tt)                                                               \
    do {                                                                        \
        const int _b = (tt) % 3;                                                \
        _Pragma("unroll")                                                       \
        for (int rr = 0; rr < 4; ++rr)                                          \
            __builtin_amdgcn_global_load_lds(                                   \
                (const __attribute__((address_space(1))) unsigned int*)(asrc[rr] + (tt) * 256), \
                (__attribute__((address_space(3))) unsigned int*)&adj_lds[_b][4 * w + rr][0],   \
                16, 0, 0);                                                      \
        __builtin_amdgcn_global_load_lds(                                       \
            (const __attribute__((address_space(1))) unsigned int*)(wsrc + (tt) * 256),         \
            (__attribute__((address_space(3))) unsigned int*)&w2_lds[_b][w * 64],               \
            4, 0, 0);                                                           \
    } while (0)

    STAGE(0);
    STAGE(1);

    for (int t = 0; t < 32; ++t) {
        const int b = t % 3;

        // 1. fast bf preloads for THIS tile (L2-hot WhbT), issued FIRST
        short8v bf[8];
#pragma unroll
        for (int k = 0; k < 8; ++k)
            bf[k] = *reinterpret_cast<const short8v*>(bsrc + t * 256 + k * 32);
        __builtin_amdgcn_sched_barrier(0);

        // 2. slow stage for tile t+2, issued AFTER (counted waits stay counted)
        if (t + 2 < 32) STAGE(t + 2);
        __builtin_amdgcn_sched_barrier(0);

        // 3. own stage(t) drained (18 = stage(t+1) 5 + bf(t) 8 + stage(t+2) 5)
        asm volatile("s_waitcnt vmcnt(18)" ::: "memory");
        __builtin_amdgcn_s_barrier();
        __builtin_amdgcn_sched_barrier(0);

        // 5. P-phase: scores for rows 0..15 x this wave's 64 cols, from LDS
#pragma unroll
        for (int pass = 0; pass < 2; ++pass) {
            const int cc = w * 8 + q + pass * 4;          // 8-col group in [0,32)
            const int g0 = (cc * 2) ^ sw, g1 = (cc * 2 + 1) ^ sw;
            const int4   A0 = *reinterpret_cast<const int4*>(&adj_lds[b][fr][g0 * 4]);
            const int4   A1 = *reinterpret_cast<const int4*>(&adj_lds[b][fr][g1 * 4]);
            const float4 W0 = *reinterpret_cast<const float4*>(&w2_lds[b][cc * 8]);
            const float4 W1 = *reinterpret_cast<const float4*>(&w2_lds[b][cc * 8 + 4]);
            float p[8]; float t_;
            t_ = wh1 + W0.x; t_ = fmaxf(t_, 0.2f * t_); p[0] = A0.x > 0 ? __builtin_exp2f(t_) : 0.f;
            t_ = wh1 + W0.y; t_ = fmaxf(t_, 0.2f * t_); p[1] = A0.y > 0 ? __builtin_exp2f(t_) : 0.f;
            t_ = wh1 + W0.z; t_ = fmaxf(t_, 0.2f * t_); p[2] = A0.z > 0 ? __builtin_exp2f(t_) : 0.f;
            t_ = wh1 + W0.w; t_ = fmaxf(t_, 0.2f * t_); p[3] = A0.w > 0 ? __builtin_exp2f(t_) : 0.f;
            t_ = wh1 + W1.x; t_ = fmaxf(t_, 0.2f * t_); p[4] = A1.x > 0 ? __builtin_exp2f(t_) : 0.f;
            t_ = wh1 + W1.y; t_ = fmaxf(t_, 0.2f * t_); p[5] = A1.y > 0 ? __builtin_exp2f(t_) : 0.f;
            t_ = wh1 + W1.z; t_ = fmaxf(t_, 0.2f * t_); p[6] = A1.z > 0 ? __builtin_exp2f(t_) : 0.f;
            t_ = wh1 + W1.w; t_ = fmaxf(t_, 0.2f * t_); p[7] = A1.w > 0 ? __builtin_exp2f(t_) : 0.f;
            lsum += ((p[0] + p[1]) + (p[2] + p[3])) + ((p[4] + p[5]) + (p[6] + p[7]));

            union { short8v s8; __hip_bfloat162 h2[4]; } u;
            u.h2[0] = __float22bfloat162_rn(float2{p[0], p[1]});
            u.h2[1] = __float22bfloat162_rn(float2{p[2], p[3]});
            u.h2[2] = __float22bfloat162_rn(float2{p[4], p[5]});
            u.h2[3] = __float22bfloat162_rn(float2{p[6], p[7]});
            *reinterpret_cast<short8v*>(&p_lds[fr][((cc ^ sw) * 8)]) = u.s8;
        }

        // 6/7. P visible to all waves
        asm volatile("s_waitcnt lgkmcnt(0)" ::: "memory");
        __builtin_amdgcn_s_barrier();
        __builtin_amdgcn_sched_barrier(0);

        // 8. MFMA: 8 k-steps; A from shared P (swizzled), B from bf regs
#pragma unroll
        for (int k = 0; k < 8; ++k) {
            short8v af = *reinterpret_cast<const short8v*>(
                &p_lds[fr][(((k * 4 + q) ^ sw) * 8)]);
            acc = __builtin_amdgcn_mfma_f32_16x16x32_bf16(af, bf[k], acc, 0, 0, 0);
        }
    }
#undef STAGE

    // ---- epilogue: row denominators across waves, normalize, ELU ----
    lsum += __shfl_xor(lsum, 16);
    lsum += __shfl_xor(lsum, 32);
    if (lane < 16) sm_l[w][lane] = lsum;
    __syncthreads();

#pragma unroll
    for (int reg = 0; reg < 4; ++reg) {
        const int R = 4 * q + reg;
        const float lrow = sm_l[0][R] + sm_l[1][R] + sm_l[2][R] + sm_l[3][R];
        float y = acc[reg] / lrow;
        y = y > 0.f ? y : expm1f(y);          // ELU, alpha=1
        out[(size_t)(i0 + R) * 64 + 16 * w + fr] = y;
    }
}

extern "C" void kernel_launch(void* const* d_in, const int* in_sizes, int n_in,
                              void* d_out, int out_size, void* d_ws, size_t ws_size,
                              hipStream_t stream) {
    const float* h   = (const float*)d_in[0];
    const int*   adj = (const int*)d_in[1];
    const float* W   = (const float*)d_in[2];
    const float* a   = (const float*)d_in[3];

    unsigned short* WhbT = (unsigned short*)d_ws;                    // 1 MB
    float* Wh1L = (float*)((char*)d_ws + (1 << 20));                 // 32 KB
    float* W2L  = Wh1L + 8192;                                       // 32 KB

    wh_kernel<<<256, 256, 0, stream>>>(h, W, a, WhbT, Wh1L, W2L);
    attn_kernel<<<512, 256, 0, stream>>>(adj, WhbT, Wh1L, W2L, (float*)d_out);
}